// Round 1
// 354.056 us; speedup vs baseline: 1.0013x; 1.0013x over previous
//
#include <hip/hip_runtime.h>

// Per-voxel LUT gather + scale + onehot, all float32.
//   out[i]     = paren[i] * scale(lab[i]), scale(0) == 1.0  (bg bit-exact)
//   onehot ch0 = lab==0, ch1 = dark vessel, ch2 = bright vessel
// Traffic: 8 B read + 16 B write per voxel -> 403 MB -> ~64 us @ 6.3 TB/s.
//
// R7: 16 voxels/thread in four 256-voxel-strided float4 groups. Each wave now
// owns a 4 KB contiguous span per stream (4 back-to-back 1 KB instructions,
// stream-major store order), doubling DRAM burst length per stream switch vs
// R6's 2 KB, and halving per-voxel instruction overhead. NT loads + NT stores
// retained (R4 A/B winner). VGPR ~105 -> ~16 waves/CU; Little's law needs only
// ~9 KB in flight/CU vs ~128 KB available, so occupancy still saturates HBM.

constexpr unsigned int VOX = 256u * 256u * 256u;  // 16,777,216
constexpr int N_IDS = 256;

typedef int   vint4  __attribute__((ext_vector_type(4)));
typedef float vflt4  __attribute__((ext_vector_type(4)));

__global__ __launch_bounds__(256)
void synth_semantic_kernel(const int* __restrict__ labels,
                           const float* __restrict__ id_intensity,
                           const int* __restrict__ id_is_dark,
                           const float* __restrict__ paren,
                           float* __restrict__ out)
{
    // LUT: bits[30:0] = f32 scale (id 0 forced to 1.0; scale in (0,2) so the
    // sign bit is free), bit 31 = dark flag. One ds_read_b32 per voxel.
    __shared__ unsigned int lut[N_IDS];
    const int t = threadIdx.x;
    {
        float sc = (t == 0) ? 1.0f : id_intensity[t];
        union { float f; unsigned int u; } cv; cv.f = sc;
        lut[t] = (cv.u & 0x7FFFFFFFu) | ((id_is_dark[t] == 1) ? 0x80000000u : 0u);
    }
    __syncthreads();

    // Wave w owns voxels [w*1024, w*1024+1024); lane l handles four float4
    // groups at w*1024 + 4l + {0,256,512,768}. Every ld/st instruction is a
    // contiguous aligned 1 KB per wave; per stream the wave touches 4 KB.
    const unsigned int lane = (unsigned int)t & 63u;
    const unsigned int wave = (blockIdx.x * 256u + (unsigned int)t) >> 6;
    const unsigned int base = wave * 1024u + lane * 4u;

    // Issue all 8 loads up front (8 KB/wave in flight).
    vint4 l[4]; vflt4 p[4];
#pragma unroll
    for (int g = 0; g < 4; ++g) {
        l[g] = __builtin_nontemporal_load((const vint4*)(labels + base + 256u * g));
        p[g] = __builtin_nontemporal_load((const vflt4*)(paren  + base + 256u * g));
    }

    vflt4 o[4], bg[4], dk[4], br[4];
#pragma unroll
    for (int g = 0; g < 4; ++g) {
        const int   labs[4] = {l[g].x, l[g].y, l[g].z, l[g].w};
        const float pv[4]   = {p[g].x, p[g].y, p[g].z, p[g].w};
        float oo[4], ob[4], od[4], orr[4];
#pragma unroll
        for (int j = 0; j < 4; ++j) {
            const int lab = labs[j];
            const unsigned int e = lut[lab];
            union { unsigned int u; float f; } sc; sc.u = e & 0x7FFFFFFFu;
            const bool isbg = (lab == 0);
            const bool isdk = (!isbg) && (e >> 31);
            const bool isbr = (!isbg) && !(e >> 31);
            oo[j]  = pv[j] * sc.f;          // bg: *1.0f, bit-exact
            ob[j]  = isbg ? 1.0f : 0.0f;
            od[j]  = isdk ? 1.0f : 0.0f;
            orr[j] = isbr ? 1.0f : 0.0f;
        }
        o[g]  = (vflt4){oo[0],  oo[1],  oo[2],  oo[3]};
        bg[g] = (vflt4){ob[0],  ob[1],  ob[2],  ob[3]};
        dk[g] = (vflt4){od[0],  od[1],  od[2],  od[3]};
        br[g] = (vflt4){orr[0], orr[1], orr[2], orr[3]};
    }

    // Stream-major stores: 4 consecutive 1 KB wave-bursts (4 KB contiguous)
    // per output stream before switching streams.
#pragma unroll
    for (int g = 0; g < 4; ++g)
        __builtin_nontemporal_store(o[g],  (vflt4*)(out + base + 256u * g));
#pragma unroll
    for (int g = 0; g < 4; ++g)
        __builtin_nontemporal_store(bg[g], (vflt4*)(out + VOX + base + 256u * g));
#pragma unroll
    for (int g = 0; g < 4; ++g)
        __builtin_nontemporal_store(dk[g], (vflt4*)(out + 2u * VOX + base + 256u * g));
#pragma unroll
    for (int g = 0; g < 4; ++g)
        __builtin_nontemporal_store(br[g], (vflt4*)(out + 3u * VOX + base + 256u * g));
}

extern "C" void kernel_launch(void* const* d_in, const int* in_sizes, int n_in,
                              void* d_out, int out_size, void* d_ws, size_t ws_size,
                              hipStream_t stream) {
    const int*   labels  = (const int*)d_in[0];
    const float* id_int  = (const float*)d_in[1];
    const int*   id_dark = (const int*)d_in[2];
    const float* paren   = (const float*)d_in[3];
    float*       outp    = (float*)d_out;

    const unsigned int threads_total = VOX / 16u;      // 1,048,576
    const unsigned int blocks = threads_total / 256u;  // 4,096
    synth_semantic_kernel<<<dim3(blocks), dim3(256), 0, stream>>>(
        labels, id_int, id_dark, paren, outp);
}